// Round 7
// baseline (204.948 us; speedup 1.0000x reference)
//
#include <hip/hip_runtime.h>
#include <hip/hip_bf16.h>

// MoE MLP (top-2 of 8 experts), T=4096 tokens, D=1024, W=1024.
// R7: weight pre-transpose ELIMINATED. B tiles are staged straight from the
// natural-layout fp32 weights (N contiguous -> coalesced column loads), cvt to
// bf16 in-register, written transposed+swizzled into LDS. pre phase = router only.
// Retained: XCD map (expert = bid&7), BK=64, ballot build_lists, combine pass.

#define T_TOKENS 4096
#define DD 1024
#define EE 8
#define WW 1024
#define CAP 1536          // per-expert capacity (expected ~1024, sigma ~28)
#define BM 128
#define BN 64
#define BK 64
#define MT (CAP / BM)     // 12 m-tiles max per expert
#define NT 16             // 1024/64 n-tiles

typedef short bf16x8 __attribute__((ext_vector_type(8)));
typedef float f32x4 __attribute__((ext_vector_type(4)));

__device__ __forceinline__ void gload_lds16(const void* g, void* l) {
  __builtin_amdgcn_global_load_lds((__attribute__((address_space(1))) void*)(g),
                                   (__attribute__((address_space(3))) void*)(l),
                                   16, 0, 0);
}

__device__ __forceinline__ float bf2f(unsigned short u) {
  union { unsigned int i; float f; } v; v.i = (unsigned int)u << 16; return v.f;
}

// ---------------- router: fp32 logits, sigmoid, top-2, fused x->bf16 ----------------
__global__ __launch_bounds__(256) void router_kernel(
    const float* __restrict__ x, const float* __restrict__ rw,
    __hip_bfloat16* __restrict__ xb, int* __restrict__ sel,
    float* __restrict__ wpair)
{
  int lane = threadIdx.x & 63;
  int wave = threadIdx.x >> 6;
  int t = blockIdx.x * 4 + wave;   // one wave per token
  const float* xrow = x + (size_t)t * DD;
  float acc[EE];
#pragma unroll
  for (int e = 0; e < EE; e++) acc[e] = 0.f;
#pragma unroll
  for (int i = 0; i < DD / 64; i++) {
    int d = lane + i * 64;
    float xv = xrow[d];
    xb[t * DD + d] = __float2bfloat16(xv);   // fused x -> bf16
#pragma unroll
    for (int e = 0; e < EE; e++) acc[e] += xv * rw[e * DD + d];
  }
#pragma unroll
  for (int e = 0; e < EE; e++) {
#pragma unroll
    for (int off = 32; off > 0; off >>= 1)
      acc[e] += __shfl_down(acc[e], off, 64);
  }
  if (lane == 0) {
    float p[EE];
#pragma unroll
    for (int e = 0; e < EE; e++) p[e] = 1.f / (1.f + expf(-acc[e]));
    // top-2, ties -> lowest index (matches jax.lax.top_k stable ordering)
    int e0 = 0; float b0 = p[0];
    for (int e = 1; e < EE; e++) if (p[e] > b0) { b0 = p[e]; e0 = e; }
    int e1 = -1; float b1 = -1.f;
    for (int e = 0; e < EE; e++) {
      if (e == e0) continue;
      if (p[e] > b1) { b1 = p[e]; e1 = e; }
    }
    float s = b0 + b1 + 1e-20f;
    sel[t] = e0 | (e1 << 8);
    wpair[2 * t]     = b0 / s;
    wpair[2 * t + 1] = b1 / s;
  }
}

// ---------------- build per-expert token lists (1 block, wave-ballot agg) ----------------
__global__ __launch_bounds__(1024) void build_lists(
    const int* __restrict__ sel, int* __restrict__ counts,
    int* __restrict__ idx, int* __restrict__ tslot)
{
  __shared__ int lcnt[EE];
  int tid = threadIdx.x, lane = tid & 63;
  if (tid < EE) lcnt[tid] = 0;
  __syncthreads();
  unsigned long long lower = (1ull << lane) - 1;
#pragma unroll
  for (int j = 0; j < T_TOKENS / 1024; j++) {
    int t = j * 1024 + tid;
    int s = sel[t];
    int e0 = s & 0xff, e1 = (s >> 8) & 0xff;
    int slot0 = 0, slot1 = 0;
#pragma unroll
    for (int e = 0; e < EE; e++) {
      unsigned long long m0 = __ballot(e0 == e);
      unsigned long long m1 = __ballot(e1 == e);
      int c0 = __popcll(m0), c1 = __popcll(m1);
      int base = 0;
      if (lane == 0 && (c0 + c1) > 0) base = atomicAdd(&lcnt[e], c0 + c1);
      base = __shfl(base, 0, 64);
      if (e0 == e) slot0 = base + __popcll(m0 & lower);
      if (e1 == e) slot1 = base + c0 + __popcll(m1 & lower);
    }
    int p0 = e0 * CAP + slot0, p1 = e1 * CAP + slot1;
    idx[p0] = t; idx[p1] = t;
    tslot[2 * t] = p0; tslot[2 * t + 1] = p1;
  }
  __syncthreads();
  if (tid < EE) counts[tid] = lcnt[tid];
}

// B-staging helper: thread (n_loc, kq) loads 16 fp32 down the K column of the
// natural-layout weight (stride ldb elems), cvt to bf16, writes 2 swizzled
// 16B granules into Bs[n][k] layout. Wave = 64 consecutive n -> coalesced.
__device__ __forceinline__ void stage_B_cvt(
    const float* __restrict__ bp, size_t ldb, short* __restrict__ Bs,
    int n_loc, int kq)
{
  float v[16];
#pragma unroll
  for (int j = 0; j < 16; j++) v[j] = bp[(size_t)j * ldb];
  union { short s[8]; bf16x8 vec; } lo, hi;
#pragma unroll
  for (int j = 0; j < 8; j++) {
    lo.s[j] = (short)__bfloat16_as_ushort(__float2bfloat16(v[j]));
    hi.s[j] = (short)__bfloat16_as_ushort(__float2bfloat16(v[j + 8]));
  }
  int sw = n_loc & 7;
  *(bf16x8*)(Bs + (n_loc * 8 + ((2 * kq) ^ sw)) * 8) = lo.vec;
  *(bf16x8*)(Bs + (n_loc * 8 + ((2 * kq + 1) ^ sw)) * 8) = hi.vec;
}

// ---------------- grouped GEMM1: h = gather(xb) @ w1[:, e-slice], act = relu(h)^2 ----------------
__global__ __launch_bounds__(256) void gemm1_kernel(
    const __hip_bfloat16* __restrict__ xb, const float* __restrict__ w1,
    const int* __restrict__ counts, const int* __restrict__ idx,
    __hip_bfloat16* __restrict__ act)
{
  __shared__ short As[BM * BK];   // 16 KB
  __shared__ short Bs[BN * BK];   // 8 KB
  int bid = blockIdx.x;
  int e = bid & 7;
  int i = bid >> 3;               // 0..MT*NT-1, nt fastest
  int mt = i >> 4, nt = i & 15;
  int n_e = counts[e];
  if (mt * BM >= n_e) return;

  int tid = threadIdx.x;
  int lane = tid & 63;
  int wave = __builtin_amdgcn_readfirstlane(tid >> 6);
  int wm = (wave >> 1) * 64, wn = (wave & 1) * 32;
  int m16 = lane & 15, qd = lane >> 4;

  // A staging: granule = 16B (8 bf16); 8 granule-cols/row; slot s -> row s>>3,
  // swizzled col (s&7)^(row&7). 4 issues/thread.
  const __hip_bfloat16* gA[4];
#pragma unroll
  for (int i2 = 0; i2 < 4; i2++) {
    int s = i2 * 256 + tid;
    int r = s >> 3;
    int q = (s & 7) ^ (r & 7);                // logical k-granule
    int rowA = mt * BM + r;
    int slot = rowA < n_e ? rowA : n_e - 1;   // clamp tail rows to valid slot
    int tok = idx[e * CAP + slot];
    gA[i2] = xb + (size_t)tok * DD + q * 8;
  }
  short* ldsA[4];
#pragma unroll
  for (int i2 = 0; i2 < 4; i2++) ldsA[i2] = As + (i2 * 256 + wave * 64) * 8;

  // B staging from natural w1 [D=1024][E*W=8192]: col = e*WW + nt*BN + n, N contig.
  int n_loc = tid & 63;
  int kq = tid >> 6;
  const float* bp = w1 + (size_t)(kq * 16) * (EE * WW)
                       + (size_t)e * WW + nt * BN + n_loc;

  int aoff[4][2], boff[2][2];
#pragma unroll
  for (int i2 = 0; i2 < 4; i2++) {
    int r = wm + i2 * 16 + m16;
#pragma unroll
    for (int h = 0; h < 2; h++)
      aoff[i2][h] = (r * 8 + ((qd + h * 4) ^ (r & 7))) * 8;
  }
#pragma unroll
  for (int j = 0; j < 2; j++) {
    int r = wn + j * 16 + m16;
#pragma unroll
    for (int h = 0; h < 2; h++)
      boff[j][h] = (r * 8 + ((qd + h * 4) ^ (r & 7))) * 8;
  }

  f32x4 zero = {0.f, 0.f, 0.f, 0.f};
  f32x4 acc[4][2];
#pragma unroll
  for (int mi = 0; mi < 4; mi++)
#pragma unroll
    for (int ni = 0; ni < 2; ni++) acc[mi][ni] = zero;

  for (int k0 = 0; k0 < DD; k0 += BK) {
    gload_lds16(gA[0] + k0, ldsA[0]);
    gload_lds16(gA[1] + k0, ldsA[1]);
    gload_lds16(gA[2] + k0, ldsA[2]);
    gload_lds16(gA[3] + k0, ldsA[3]);
    stage_B_cvt(bp, EE * WW, Bs, n_loc, kq);
    bp += (size_t)BK * (EE * WW);
    __syncthreads();
#pragma unroll
    for (int h = 0; h < 2; h++) {
      bf16x8 af[4], bfr[2];
#pragma unroll
      for (int i2 = 0; i2 < 4; i2++) af[i2] = *(const bf16x8*)(As + aoff[i2][h]);
#pragma unroll
      for (int j = 0; j < 2; j++) bfr[j] = *(const bf16x8*)(Bs + boff[j][h]);
#pragma unroll
      for (int mi = 0; mi < 4; mi++)
#pragma unroll
        for (int ni = 0; ni < 2; ni++)
          acc[mi][ni] = __builtin_amdgcn_mfma_f32_16x16x32_bf16(
              af[mi], bfr[ni], acc[mi][ni], 0, 0, 0);
    }
    __syncthreads();
  }

  // epilogue: relu^2 -> bf16 act[(e*CAP + slot)][col]
#pragma unroll
  for (int mi = 0; mi < 4; mi++) {
#pragma unroll
    for (int reg = 0; reg < 4; reg++) {
      int rowt = mt * BM + wm + mi * 16 + qd * 4 + reg;
      if (rowt < n_e) {
#pragma unroll
        for (int ni = 0; ni < 2; ni++) {
          float v = acc[mi][ni][reg];
          v = v > 0.f ? v * v : 0.f;
          int col = nt * BN + wn + ni * 16 + m16;
          act[((size_t)e * CAP + rowt) * WW + col] = __float2bfloat16(v);
        }
      }
    }
  }
}

// ---------------- grouped GEMM2: y = act @ w2[e-slice] (raw bf16 y) ----------------
__global__ __launch_bounds__(256) void gemm2_kernel(
    const __hip_bfloat16* __restrict__ act, const float* __restrict__ w2,
    const int* __restrict__ counts, __hip_bfloat16* __restrict__ y)
{
  __shared__ short As[BM * BK];
  __shared__ short Bs[BN * BK];
  int bid = blockIdx.x;
  int e = bid & 7;
  int i = bid >> 3;
  int mt = i >> 4, nt = i & 15;
  int n_e = counts[e];
  if (mt * BM >= n_e) return;

  int tid = threadIdx.x;
  int lane = tid & 63;
  int wave = __builtin_amdgcn_readfirstlane(tid >> 6);
  int wm = (wave >> 1) * 64, wn = (wave & 1) * 32;
  int m16 = lane & 15, qd = lane >> 4;

  const __hip_bfloat16* gA[4];
#pragma unroll
  for (int i2 = 0; i2 < 4; i2++) {
    int s = i2 * 256 + tid;
    int r = s >> 3;
    int q = (s & 7) ^ (r & 7);
    gA[i2] = act + ((size_t)e * CAP + mt * BM + r) * WW + q * 8;  // rows >= n_e: garbage, row-isolated
  }
  short* ldsA[4];
#pragma unroll
  for (int i2 = 0; i2 < 4; i2++) ldsA[i2] = As + (i2 * 256 + wave * 64) * 8;

  // B staging from natural w2 [E*W][D]: row = e*WW + k, col = nt*BN + n (contig).
  int n_loc = tid & 63;
  int kq = tid >> 6;
  const float* bp = w2 + ((size_t)e * WW + kq * 16) * DD + nt * BN + n_loc;

  int aoff[4][2], boff[2][2];
#pragma unroll
  for (int i2 = 0; i2 < 4; i2++) {
    int r = wm + i2 * 16 + m16;
#pragma unroll
    for (int h = 0; h < 2; h++)
      aoff[i2][h] = (r * 8 + ((qd + h * 4) ^ (r & 7))) * 8;
  }
#pragma unroll
  for (int j = 0; j < 2; j++) {
    int r = wn + j * 16 + m16;
#pragma unroll
    for (int h = 0; h < 2; h++)
      boff[j][h] = (r * 8 + ((qd + h * 4) ^ (r & 7))) * 8;
  }

  f32x4 zero = {0.f, 0.f, 0.f, 0.f};
  f32x4 acc[4][2];
#pragma unroll
  for (int mi = 0; mi < 4; mi++)
#pragma unroll
    for (int ni = 0; ni < 2; ni++) acc[mi][ni] = zero;

  for (int k0 = 0; k0 < WW; k0 += BK) {
    gload_lds16(gA[0] + k0, ldsA[0]);
    gload_lds16(gA[1] + k0, ldsA[1]);
    gload_lds16(gA[2] + k0, ldsA[2]);
    gload_lds16(gA[3] + k0, ldsA[3]);
    stage_B_cvt(bp, DD, Bs, n_loc, kq);
    bp += (size_t)BK * DD;
    __syncthreads();
#pragma unroll
    for (int h = 0; h < 2; h++) {
      bf16x8 af[4], bfr[2];
#pragma unroll
      for (int i2 = 0; i2 < 4; i2++) af[i2] = *(const bf16x8*)(As + aoff[i2][h]);
#pragma unroll
      for (int j = 0; j < 2; j++) bfr[j] = *(const bf16x8*)(Bs + boff[j][h]);
#pragma unroll
      for (int mi = 0; mi < 4; mi++)
#pragma unroll
        for (int ni = 0; ni < 2; ni++)
          acc[mi][ni] = __builtin_amdgcn_mfma_f32_16x16x32_bf16(
              af[mi], bfr[ni], acc[mi][ni], 0, 0, 0);
    }
    __syncthreads();
  }

  // epilogue: raw y (weights applied in combine)
#pragma unroll
  for (int mi = 0; mi < 4; mi++) {
#pragma unroll
    for (int reg = 0; reg < 4; reg++) {
      int slot = mt * BM + wm + mi * 16 + qd * 4 + reg;
      if (slot < n_e) {
#pragma unroll
        for (int ni = 0; ni < 2; ni++) {
          int col = nt * BN + wn + ni * 16 + m16;
          y[((size_t)e * CAP + slot) * DD + col] = __float2bfloat16(acc[mi][ni][reg]);
        }
      }
    }
  }
}

// ---------------- combine: out[t] = w0*y[slot0] + w1*y[slot1] ----------------
__global__ __launch_bounds__(256) void combine_kernel(
    const __hip_bfloat16* __restrict__ y, const int* __restrict__ tslot,
    const float* __restrict__ wpair, float* __restrict__ out)
{
  int t = blockIdx.x;
  int c = threadIdx.x * 4;
  int s0 = tslot[2 * t], s1 = tslot[2 * t + 1];
  float w0 = wpair[2 * t], w1 = wpair[2 * t + 1];
  const unsigned short* yu = (const unsigned short*)y;
  ushort4 a = *(const ushort4*)(yu + (size_t)s0 * DD + c);
  ushort4 bq = *(const ushort4*)(yu + (size_t)s1 * DD + c);
  f32x4 o;
  o[0] = w0 * bf2f(a.x) + w1 * bf2f(bq.x);
  o[1] = w0 * bf2f(a.y) + w1 * bf2f(bq.y);
  o[2] = w0 * bf2f(a.z) + w1 * bf2f(bq.z);
  o[3] = w0 * bf2f(a.w) + w1 * bf2f(bq.w);
  *(f32x4*)(out + (size_t)t * DD + c) = o;
}

extern "C" void kernel_launch(void* const* d_in, const int* in_sizes, int n_in,
                              void* d_out, int out_size, void* d_ws, size_t ws_size,
                              hipStream_t stream)
{
  const float* x  = (const float*)d_in[0];
  const float* rw = (const float*)d_in[1];
  const float* w1 = (const float*)d_in[2];
  const float* w2 = (const float*)d_in[3];
  float* out = (float*)d_out;

  char* ws = (char*)d_ws;
  __hip_bfloat16* xb  = (__hip_bfloat16*)ws;  ws += (size_t)T_TOKENS * DD * 2;
  __hip_bfloat16* act = (__hip_bfloat16*)ws;  ws += (size_t)EE * CAP * WW * 2;
  __hip_bfloat16* y   = (__hip_bfloat16*)ws;  ws += (size_t)EE * CAP * DD * 2;
  int*   counts = (int*)ws;                   ws += 256;
  int*   idx    = (int*)ws;                   ws += (size_t)EE * CAP * 4;
  int*   sel    = (int*)ws;                   ws += (size_t)T_TOKENS * 4;
  int*   tslot  = (int*)ws;                   ws += (size_t)T_TOKENS * 8;
  float* wpair  = (float*)ws;                 ws += (size_t)T_TOKENS * 8;

  router_kernel<<<T_TOKENS / 4, 256, 0, stream>>>(x, rw, xb, sel, wpair);
  build_lists<<<1, 1024, 0, stream>>>(sel, counts, idx, tslot);
  gemm1_kernel<<<EE * MT * NT, 256, 0, stream>>>(xb, w1, counts, idx, act);
  gemm2_kernel<<<EE * MT * NT, 256, 0, stream>>>(act, w2, counts, y);
  combine_kernel<<<T_TOKENS, 256, 0, stream>>>(y, tslot, wpair, out);
}